// Round 1
// baseline (87.978 us; speedup 1.0000x reference)
//
#include <hip/hip_runtime.h>
#include <math.h>

#define BB 32768
#define CC 8
#define HH 128
#define RR 16

__global__ __launch_bounds__(128) void gru_cell_kernel(
    const float* __restrict__ x,
    const float* __restrict__ h,
    const float* __restrict__ U,
    const float* __restrict__ V,
    const float* __restrict__ bias_ih,
    const float* __restrict__ bias_hh,
    float* __restrict__ out)
{
    const int b = blockIdx.x;
    const int i = threadIdx.x; // 0..127 = output feature

    __shared__ float hs[HH];
    __shared__ float xs[CC];
    __shared__ float vh[RR];

    const float h_i = h[b * HH + i];
    hs[i] = h_i;
    if (i < CC) xs[i] = x[b * CC + i];
    __syncthreads();

    float g_r = 0.f, g_z = 0.f, g_n = 0.f;     // rec contributions
    float bi_r = 0.f, bi_z = 0.f, bi_n = 0.f;  // x @ bias_ih
    float bh_r = 0.f, bh_z = 0.f, bh_n = 0.f;  // x @ bias_hh

    for (int c = 0; c < CC; ++c) {
        const float w = xs[c];           // uniform across block
        if (w != 0.f) {                  // uniform branch -> syncthreads safe
            // Vh[r] = sum_j V[c,j,r] * h[j]   (16 lanes active)
            if (i < RR) {
                const float* Vp = V + c * HH * RR + i;
                float a0 = 0.f, a1 = 0.f, a2 = 0.f, a3 = 0.f;
                #pragma unroll
                for (int j = 0; j < HH; j += 4) {
                    a0 += Vp[(j + 0) * RR] * hs[j + 0];
                    a1 += Vp[(j + 1) * RR] * hs[j + 1];
                    a2 += Vp[(j + 2) * RR] * hs[j + 2];
                    a3 += Vp[(j + 3) * RR] * hs[j + 3];
                }
                vh[i] = (a0 + a1) + (a2 + a3);
            }
            __syncthreads();

            // rec gate dots: U[c, g, :] . vh
            const float* Up = U + c * 3 * HH * RR;
            float s_r = 0.f, s_z = 0.f, s_n = 0.f;
            #pragma unroll
            for (int r = 0; r < RR; ++r) s_r += Up[(i           ) * RR + r] * vh[r];
            #pragma unroll
            for (int r = 0; r < RR; ++r) s_z += Up[(HH + i      ) * RR + r] * vh[r];
            #pragma unroll
            for (int r = 0; r < RR; ++r) s_n += Up[(2 * HH + i  ) * RR + r] * vh[r];
            g_r += w * s_r;
            g_z += w * s_z;
            g_n += w * s_n;

            bi_r += w * bias_ih[c * 3 * HH + i];
            bi_z += w * bias_ih[c * 3 * HH + HH + i];
            bi_n += w * bias_ih[c * 3 * HH + 2 * HH + i];
            bh_r += w * bias_hh[c * 3 * HH + i];
            bh_z += w * bias_hh[c * 3 * HH + HH + i];
            bh_n += w * bias_hh[c * 3 * HH + 2 * HH + i];

            __syncthreads();   // protect vh before next c overwrites it
        }
    }

    const float rg = 1.f / (1.f + __expf(-(bi_r + g_r + bh_r)));
    const float zg = 1.f / (1.f + __expf(-(bi_z + g_z + bh_z)));
    const float ng = tanhf(bi_n + rg * (g_n + bh_n));
    out[b * HH + i] = (1.f - zg) * ng + zg * h_i;
}

extern "C" void kernel_launch(void* const* d_in, const int* in_sizes, int n_in,
                              void* d_out, int out_size, void* d_ws, size_t ws_size,
                              hipStream_t stream) {
    const float* x       = (const float*)d_in[0];
    const float* h       = (const float*)d_in[1];
    const float* U       = (const float*)d_in[2];
    const float* V       = (const float*)d_in[3];
    const float* bias_ih = (const float*)d_in[4];
    const float* bias_hh = (const float*)d_in[5];
    float* out = (float*)d_out;

    gru_cell_kernel<<<BB, HH, 0, stream>>>(x, h, U, V, bias_ih, bias_hh, out);
}

// Round 2
// 62.902 us; speedup vs baseline: 1.3986x; 1.3986x over previous
//
#include <hip/hip_runtime.h>
#include <math.h>

#define BB 32768
#define CC 8
#define HH 128
#define RR 16
#define GG (3 * HH)          // 384
#define TT 64                // rows per tile in pass 2
#define NTILES (BB / TT)     // 512

// ---------------- pass 0: zero bucket counters ----------------
__global__ void zero_cnt_kernel(int* __restrict__ cnt) {
    if (threadIdx.x < CC) cnt[threadIdx.x] = 0;
}

// ---------------- pass 1: bucket rows by condition ----------------
__global__ __launch_bounds__(256) void bucket_kernel(
    const float* __restrict__ x, int* __restrict__ cnt, int* __restrict__ rows)
{
    __shared__ int lcnt[CC];
    __shared__ int lbase[CC];
    const int tid = threadIdx.x;
    const int b = blockIdx.x * 256 + tid;

    if (tid < CC) lcnt[tid] = 0;
    __syncthreads();

    const float4 x0 = *(const float4*)(x + b * CC);
    const float4 x1 = *(const float4*)(x + b * CC + 4);
    int c = 0;
    if      (x0.x != 0.f) c = 0;
    else if (x0.y != 0.f) c = 1;
    else if (x0.z != 0.f) c = 2;
    else if (x0.w != 0.f) c = 3;
    else if (x1.x != 0.f) c = 4;
    else if (x1.y != 0.f) c = 5;
    else if (x1.z != 0.f) c = 6;
    else if (x1.w != 0.f) c = 7;

    const int mypos = atomicAdd(&lcnt[c], 1);
    __syncthreads();
    if (tid < CC) lbase[tid] = atomicAdd(&cnt[tid], lcnt[tid]);
    __syncthreads();
    rows[c * BB + lbase[c] + mypos] = b;
}

// ---------------- pass 2: per-condition tiled GRU ----------------
__device__ __forceinline__ float sigmoidf_fast(float v) {
    return 1.f / (1.f + __expf(-v));
}
__device__ __forceinline__ float tanhf_fast(float v) {
    // tanh(x) = 2*sigmoid(2x) - 1
    return 2.f / (1.f + __expf(-2.f * v)) - 1.f;
}

__global__ __launch_bounds__(256) void gru_tile_kernel(
    const float* __restrict__ x, const float* __restrict__ h,
    const float* __restrict__ U, const float* __restrict__ V,
    const float* __restrict__ bih, const float* __restrict__ bhh,
    const int* __restrict__ cnt, const int* __restrict__ rows,
    float* __restrict__ out)
{
    const int c = blockIdx.y;
    const int n = cnt[c];
    const int start = blockIdx.x * TT;
    if (start >= n) return;   // whole-block uniform early exit

    __shared__ float Vt[RR][HH + 4];    // V_c transposed, padded (8.4 KB)
    __shared__ float pq[4][TT][RR + 1]; // quarter partials, padded (17.4 KB)
    __shared__ float vhs[TT][RR];       // Vh * w  (4 KB)
    __shared__ int   rloc[TT];
    __shared__ float wloc[TT];

    const int tid = threadIdx.x;

    // stage row indices + weights
    if (tid < TT) {
        const int idx = start + tid;
        const int b = (idx < n) ? rows[c * BB + idx] : -1;
        rloc[tid] = b;
        wloc[tid] = (b >= 0) ? x[b * CC + c] : 0.f;
    }
    // stage Vt: V is [c][j][r] -> Vt[r][j]
    for (int idx = tid; idx < HH * RR; idx += 256) {
        const int j = idx / RR, r = idx % RR;
        Vt[r][j] = V[c * HH * RR + idx];
    }
    __syncthreads();

    // ---- phase A: Vh quarter-partials; h loaded straight to registers ----
    {
        const int row = tid & 63;
        const int q   = tid >> 6;   // 0..3 == wave id
        const int b   = rloc[row];
        float hreg[32];
        if (b >= 0) {
            const float* hp = h + b * HH + q * 32;
            #pragma unroll
            for (int j4 = 0; j4 < 8; ++j4) {
                const float4 v = *(const float4*)(hp + j4 * 4);
                hreg[j4 * 4 + 0] = v.x; hreg[j4 * 4 + 1] = v.y;
                hreg[j4 * 4 + 2] = v.z; hreg[j4 * 4 + 3] = v.w;
            }
        } else {
            #pragma unroll
            for (int j = 0; j < 32; ++j) hreg[j] = 0.f;
        }
        #pragma unroll
        for (int r = 0; r < RR; ++r) {
            float s = 0.f;
            #pragma unroll
            for (int j = 0; j < 32; ++j) s += Vt[r][q * 32 + j] * hreg[j];
            pq[q][row][r] = s;
        }
    }
    __syncthreads();

    // reduce quarters, fold w
    for (int idx = tid; idx < TT * RR; idx += 256) {
        const int row = idx / RR, r = idx % RR;
        const float s = pq[0][row][r] + pq[1][row][r] + pq[2][row][r] + pq[3][row][r];
        vhs[row][r] = s * wloc[row];
    }
    __syncthreads();

    // ---- phase B: gates; U rows live in registers, reused across 32 rows ----
    const int i    = tid & 127;
    const int half = tid >> 7;    // 0 or 1
    const float* Up = U + c * GG * RR;

    float ur[RR], uz[RR], un[RR];
    #pragma unroll
    for (int k = 0; k < 4; ++k) {
        const float4 a = *(const float4*)(Up + i * RR + 4 * k);
        ur[4*k+0] = a.x; ur[4*k+1] = a.y; ur[4*k+2] = a.z; ur[4*k+3] = a.w;
        const float4 bq = *(const float4*)(Up + (HH + i) * RR + 4 * k);
        uz[4*k+0] = bq.x; uz[4*k+1] = bq.y; uz[4*k+2] = bq.z; uz[4*k+3] = bq.w;
        const float4 cq = *(const float4*)(Up + (2 * HH + i) * RR + 4 * k);
        un[4*k+0] = cq.x; un[4*k+1] = cq.y; un[4*k+2] = cq.z; un[4*k+3] = cq.w;
    }
    const float bihr = bih[c * GG + i];
    const float bihz = bih[c * GG + HH + i];
    const float bihn = bih[c * GG + 2 * HH + i];
    const float bhhr = bhh[c * GG + i];
    const float bhhz = bhh[c * GG + HH + i];
    const float bhhn = bhh[c * GG + 2 * HH + i];

    for (int m = 0; m < 32; ++m) {
        const int row = half * 32 + m;   // wave-uniform
        const int b = rloc[row];
        if (b < 0) continue;             // wave-uniform branch
        const float w = wloc[row];

        const float4* vrow = (const float4*)&vhs[row][0];
        const float4 v0 = vrow[0], v1 = vrow[1], v2 = vrow[2], v3 = vrow[3];

        float sr, sz, sn;
        sr  = ur[0]*v0.x + ur[1]*v0.y + ur[2]*v0.z + ur[3]*v0.w;
        sr += ur[4]*v1.x + ur[5]*v1.y + ur[6]*v1.z + ur[7]*v1.w;
        sr += ur[8]*v2.x + ur[9]*v2.y + ur[10]*v2.z + ur[11]*v2.w;
        sr += ur[12]*v3.x + ur[13]*v3.y + ur[14]*v3.z + ur[15]*v3.w;
        sz  = uz[0]*v0.x + uz[1]*v0.y + uz[2]*v0.z + uz[3]*v0.w;
        sz += uz[4]*v1.x + uz[5]*v1.y + uz[6]*v1.z + uz[7]*v1.w;
        sz += uz[8]*v2.x + uz[9]*v2.y + uz[10]*v2.z + uz[11]*v2.w;
        sz += uz[12]*v3.x + uz[13]*v3.y + uz[14]*v3.z + uz[15]*v3.w;
        sn  = un[0]*v0.x + un[1]*v0.y + un[2]*v0.z + un[3]*v0.w;
        sn += un[4]*v1.x + un[5]*v1.y + un[6]*v1.z + un[7]*v1.w;
        sn += un[8]*v2.x + un[9]*v2.y + un[10]*v2.z + un[11]*v2.w;
        sn += un[12]*v3.x + un[13]*v3.y + un[14]*v3.z + un[15]*v3.w;

        const float rg = sigmoidf_fast(sr + w * (bihr + bhhr));
        const float zg = sigmoidf_fast(sz + w * (bihz + bhhz));
        const float ng = tanhf_fast(w * bihn + rg * (sn + w * bhhn));
        const float hv = h[b * HH + i];
        out[b * HH + i] = (1.f - zg) * ng + zg * hv;
    }
}

// ---------------- fallback (round-1 kernel) if ws too small ----------------
__global__ __launch_bounds__(128) void gru_cell_naive(
    const float* __restrict__ x, const float* __restrict__ h,
    const float* __restrict__ U, const float* __restrict__ V,
    const float* __restrict__ bias_ih, const float* __restrict__ bias_hh,
    float* __restrict__ out)
{
    const int b = blockIdx.x;
    const int i = threadIdx.x;
    __shared__ float hs[HH];
    __shared__ float xs[CC];
    __shared__ float vh[RR];
    const float h_i = h[b * HH + i];
    hs[i] = h_i;
    if (i < CC) xs[i] = x[b * CC + i];
    __syncthreads();
    float g_r = 0.f, g_z = 0.f, g_n = 0.f;
    float bi_r = 0.f, bi_z = 0.f, bi_n = 0.f;
    float bh_r = 0.f, bh_z = 0.f, bh_n = 0.f;
    for (int c = 0; c < CC; ++c) {
        const float w = xs[c];
        if (w != 0.f) {
            if (i < RR) {
                const float* Vp = V + c * HH * RR + i;
                float a0 = 0.f;
                for (int j = 0; j < HH; ++j) a0 += Vp[j * RR] * hs[j];
                vh[i] = a0;
            }
            __syncthreads();
            const float* Up = U + c * 3 * HH * RR;
            float s_r = 0.f, s_z = 0.f, s_n = 0.f;
            for (int r = 0; r < RR; ++r) s_r += Up[i * RR + r] * vh[r];
            for (int r = 0; r < RR; ++r) s_z += Up[(HH + i) * RR + r] * vh[r];
            for (int r = 0; r < RR; ++r) s_n += Up[(2 * HH + i) * RR + r] * vh[r];
            g_r += w * s_r; g_z += w * s_z; g_n += w * s_n;
            bi_r += w * bias_ih[c * GG + i];
            bi_z += w * bias_ih[c * GG + HH + i];
            bi_n += w * bias_ih[c * GG + 2 * HH + i];
            bh_r += w * bias_hh[c * GG + i];
            bh_z += w * bias_hh[c * GG + HH + i];
            bh_n += w * bias_hh[c * GG + 2 * HH + i];
            __syncthreads();
        }
    }
    const float rg = 1.f / (1.f + __expf(-(bi_r + g_r + bh_r)));
    const float zg = 1.f / (1.f + __expf(-(bi_z + g_z + bh_z)));
    const float ng = tanhf(bi_n + rg * (g_n + bh_n));
    out[b * HH + i] = (1.f - zg) * ng + zg * h_i;
}

extern "C" void kernel_launch(void* const* d_in, const int* in_sizes, int n_in,
                              void* d_out, int out_size, void* d_ws, size_t ws_size,
                              hipStream_t stream) {
    const float* x       = (const float*)d_in[0];
    const float* h       = (const float*)d_in[1];
    const float* U       = (const float*)d_in[2];
    const float* V       = (const float*)d_in[3];
    const float* bias_ih = (const float*)d_in[4];
    const float* bias_hh = (const float*)d_in[5];
    float* out = (float*)d_out;

    const size_t needed = 256 + (size_t)BB * CC * sizeof(int);
    if (ws_size < needed) {
        gru_cell_naive<<<BB, HH, 0, stream>>>(x, h, U, V, bias_ih, bias_hh, out);
        return;
    }

    int* cnt  = (int*)d_ws;
    int* rows = (int*)((char*)d_ws + 256);

    zero_cnt_kernel<<<1, 64, 0, stream>>>(cnt);
    bucket_kernel<<<BB / 256, 256, 0, stream>>>(x, cnt, rows);
    dim3 grid(NTILES, CC);
    gru_tile_kernel<<<grid, 256, 0, stream>>>(x, h, U, V, bias_ih, bias_hh,
                                              cnt, rows, out);
}

// Round 3
// 42.860 us; speedup vs baseline: 2.0527x; 1.4676x over previous
//
#include <hip/hip_runtime.h>
#include <math.h>

#define BB 32768
#define CC 8
#define HH 128
#define RR 16
#define GG (3 * HH)                    // 384
#define TT 16                          // rows per tile
#define MAXTILES ((BB / TT) + CC - 1)  // 2055 upper bound on sum of per-bucket tiles

__device__ __forceinline__ float sigmoidf_fast(float v) {
    return 1.f / (1.f + __expf(-v));
}
__device__ __forceinline__ float tanhf_fast(float v) {
    return 2.f / (1.f + __expf(-2.f * v)) - 1.f;
}

// ---------------- pass 1: bucket rows by condition ----------------
__global__ __launch_bounds__(256) void bucket_kernel(
    const float* __restrict__ x, int* __restrict__ cnt, int* __restrict__ rows)
{
    __shared__ int lcnt[CC];
    __shared__ int lbase[CC];
    const int tid = threadIdx.x;
    const int b = blockIdx.x * 256 + tid;

    if (tid < CC) lcnt[tid] = 0;
    __syncthreads();

    const float4 x0 = *(const float4*)(x + b * CC);
    const float4 x1 = *(const float4*)(x + b * CC + 4);
    int c = 0;
    if      (x0.x != 0.f) c = 0;
    else if (x0.y != 0.f) c = 1;
    else if (x0.z != 0.f) c = 2;
    else if (x0.w != 0.f) c = 3;
    else if (x1.x != 0.f) c = 4;
    else if (x1.y != 0.f) c = 5;
    else if (x1.z != 0.f) c = 6;
    else if (x1.w != 0.f) c = 7;

    const int mypos = atomicAdd(&lcnt[c], 1);
    __syncthreads();
    if (tid < CC) lbase[tid] = atomicAdd(&cnt[tid], lcnt[tid]);
    __syncthreads();
    rows[c * BB + lbase[c] + mypos] = b;
}

// ---------------- pass 2: per-condition tiled GRU ----------------
__global__ __launch_bounds__(256, 4) void gru_tile_kernel(
    const float* __restrict__ x, const float* __restrict__ h,
    const float* __restrict__ U, const float* __restrict__ V,
    const float* __restrict__ bih, const float* __restrict__ bhh,
    const int* __restrict__ cnt, const int* __restrict__ rows,
    float* __restrict__ out)
{
    // ---- per-block tile descriptor from cnt[8] (scalar, ~40 ops) ----
    int ncs[CC], tcs[CC];
    #pragma unroll
    for (int q = 0; q < CC; ++q) { ncs[q] = cnt[q]; tcs[q] = (ncs[q] + TT - 1) / TT; }
    const int t = blockIdx.x;
    int c = -1, start = 0, nc = 0, base = 0;
    #pragma unroll
    for (int q = 0; q < CC; ++q) {
        if (c < 0 && t < base + tcs[q]) { c = q; start = (t - base) * TT; nc = ncs[q]; }
        base += tcs[q];
    }
    if (c < 0) return;  // t >= total tiles (<= CC-1 such blocks)

    __shared__ __align__(16) float hs[TT][HH + 4];   // 8.25 KB, stride 132w (16B-mult)
    __shared__ __align__(16) float Vt[RR][HH + 4];   // 8.25 KB
    __shared__ __align__(16) float vhs[TT][20];      // 1.25 KB, stride 80B
    __shared__ int   rloc[TT];
    __shared__ float wloc[TT];

    const int tid = threadIdx.x;

    // stage row indices + weights (threads 0..15)
    if (tid < TT) {
        const int idx = start + tid;
        const int b = (idx < nc) ? rows[c * BB + idx] : -1;
        rloc[tid] = b;
        wloc[tid] = (b >= 0) ? x[b * CC + c] : 0.f;
    }

    // stage Vt (transposed V_c): 2048 floats, 8 per thread
    {
        const float* Vc = V + c * HH * RR;
        #pragma unroll
        for (int k = 0; k < 2; ++k) {
            const int m4 = (tid * 2 + k) * 4;   // element offset in V_c
            const int j  = m4 >> 4;             // /RR
            const int r0 = m4 & 15;
            const float4 v = *(const float4*)(Vc + m4);
            Vt[r0 + 0][j] = v.x; Vt[r0 + 1][j] = v.y;
            Vt[r0 + 2][j] = v.z; Vt[r0 + 3][j] = v.w;
        }
    }

    // stage hs: thread -> (row, seg), 8 floats; re-derive b to avoid a sync
    {
        const int row = tid >> 4, seg = tid & 15;
        const int idx = start + row;
        const int b = (idx < nc) ? rows[c * BB + idx] : -1;
        if (b >= 0) {
            const float4 h0 = *(const float4*)(h + b * HH + seg * 8);
            const float4 h1 = *(const float4*)(h + b * HH + seg * 8 + 4);
            *(float4*)&hs[row][seg * 8]     = h0;
            *(float4*)&hs[row][seg * 8 + 4] = h1;
        } else {
            const float4 z = make_float4(0.f, 0.f, 0.f, 0.f);
            *(float4*)&hs[row][seg * 8]     = z;
            *(float4*)&hs[row][seg * 8 + 4] = z;
        }
    }
    __syncthreads();

    // ---- phase A: vhs[row][r] = w_row * (V_c[:,r] . h_row), 1 dot/thread ----
    {
        const int row = tid >> 4;   // 0..15
        const int r   = tid & 15;
        float s0 = 0.f, s1 = 0.f;
        #pragma unroll
        for (int j4 = 0; j4 < HH / 8; ++j4) {
            const float4 ha = *(const float4*)&hs[row][j4 * 8];
            const float4 va = *(const float4*)&Vt[r][j4 * 8];
            const float4 hb = *(const float4*)&hs[row][j4 * 8 + 4];
            const float4 vb = *(const float4*)&Vt[r][j4 * 8 + 4];
            s0 += ha.x * va.x + ha.y * va.y + ha.z * va.z + ha.w * va.w;
            s1 += hb.x * vb.x + hb.y * vb.y + hb.z * vb.z + hb.w * vb.w;
        }
        vhs[row][r] = (s0 + s1) * wloc[row];
    }
    __syncthreads();

    // ---- phase B: gates; U rows register-resident, reused across 8 rows ----
    const int i    = tid & 127;
    const int half = tid >> 7;
    const float* Up = U + c * GG * RR;

    float ur[RR], uz[RR], un[RR];
    #pragma unroll
    for (int k = 0; k < 4; ++k) {
        const float4 a  = *(const float4*)(Up + i * RR + 4 * k);
        ur[4*k+0] = a.x;  ur[4*k+1] = a.y;  ur[4*k+2] = a.z;  ur[4*k+3] = a.w;
        const float4 bq = *(const float4*)(Up + (HH + i) * RR + 4 * k);
        uz[4*k+0] = bq.x; uz[4*k+1] = bq.y; uz[4*k+2] = bq.z; uz[4*k+3] = bq.w;
        const float4 cq = *(const float4*)(Up + (2 * HH + i) * RR + 4 * k);
        un[4*k+0] = cq.x; un[4*k+1] = cq.y; un[4*k+2] = cq.z; un[4*k+3] = cq.w;
    }
    const float bsr = bih[c * GG + i]          + bhh[c * GG + i];
    const float bsz = bih[c * GG + HH + i]     + bhh[c * GG + HH + i];
    const float bin = bih[c * GG + 2 * HH + i];
    const float bhn = bhh[c * GG + 2 * HH + i];

    #pragma unroll
    for (int m = 0; m < 8; ++m) {
        const int row = half * 8 + m;        // wave-uniform
        const int b = rloc[row];
        if (b < 0) continue;                 // wave-uniform branch
        const float w = wloc[row];

        const float4 v0 = *(const float4*)&vhs[row][0];
        const float4 v1 = *(const float4*)&vhs[row][4];
        const float4 v2 = *(const float4*)&vhs[row][8];
        const float4 v3 = *(const float4*)&vhs[row][12];

        float sra = v0.x*ur[0] + v0.y*ur[1] + v0.z*ur[2] + v0.w*ur[3];
        float srb = v1.x*ur[4] + v1.y*ur[5] + v1.z*ur[6] + v1.w*ur[7];
        sra += v2.x*ur[8]  + v2.y*ur[9]  + v2.z*ur[10] + v2.w*ur[11];
        srb += v3.x*ur[12] + v3.y*ur[13] + v3.z*ur[14] + v3.w*ur[15];
        float sza = v0.x*uz[0] + v0.y*uz[1] + v0.z*uz[2] + v0.w*uz[3];
        float szb = v1.x*uz[4] + v1.y*uz[5] + v1.z*uz[6] + v1.w*uz[7];
        sza += v2.x*uz[8]  + v2.y*uz[9]  + v2.z*uz[10] + v2.w*uz[11];
        szb += v3.x*uz[12] + v3.y*uz[13] + v3.z*uz[14] + v3.w*uz[15];
        float sna = v0.x*un[0] + v0.y*un[1] + v0.z*un[2] + v0.w*un[3];
        float snb = v1.x*un[4] + v1.y*un[5] + v1.z*un[6] + v1.w*un[7];
        sna += v2.x*un[8]  + v2.y*un[9]  + v2.z*un[10] + v2.w*un[11];
        snb += v3.x*un[12] + v3.y*un[13] + v3.z*un[14] + v3.w*un[15];

        const float rg = sigmoidf_fast((sra + srb) + w * bsr);
        const float zg = sigmoidf_fast((sza + szb) + w * bsz);
        const float ng = tanhf_fast(w * bin + rg * ((sna + snb) + w * bhn));
        const float hv = hs[row][i];
        out[b * HH + i] = (1.f - zg) * ng + zg * hv;
    }
}

// ---------------- fallback (round-1 kernel) if ws too small ----------------
__global__ __launch_bounds__(128) void gru_cell_naive(
    const float* __restrict__ x, const float* __restrict__ h,
    const float* __restrict__ U, const float* __restrict__ V,
    const float* __restrict__ bias_ih, const float* __restrict__ bias_hh,
    float* __restrict__ out)
{
    const int b = blockIdx.x;
    const int i = threadIdx.x;
    __shared__ float hsn[HH];
    __shared__ float xsn[CC];
    __shared__ float vhn[RR];
    const float h_i = h[b * HH + i];
    hsn[i] = h_i;
    if (i < CC) xsn[i] = x[b * CC + i];
    __syncthreads();
    float g_r = 0.f, g_z = 0.f, g_n = 0.f;
    float bi_r = 0.f, bi_z = 0.f, bi_n = 0.f;
    float bh_r = 0.f, bh_z = 0.f, bh_n = 0.f;
    for (int c = 0; c < CC; ++c) {
        const float w = xsn[c];
        if (w != 0.f) {
            if (i < RR) {
                const float* Vp = V + c * HH * RR + i;
                float a0 = 0.f;
                for (int j = 0; j < HH; ++j) a0 += Vp[j * RR] * hsn[j];
                vhn[i] = a0;
            }
            __syncthreads();
            const float* Up = U + c * 3 * HH * RR;
            float s_r = 0.f, s_z = 0.f, s_n = 0.f;
            for (int r = 0; r < RR; ++r) s_r += Up[i * RR + r] * vhn[r];
            for (int r = 0; r < RR; ++r) s_z += Up[(HH + i) * RR + r] * vhn[r];
            for (int r = 0; r < RR; ++r) s_n += Up[(2 * HH + i) * RR + r] * vhn[r];
            g_r += w * s_r; g_z += w * s_z; g_n += w * s_n;
            bi_r += w * bias_ih[c * GG + i];
            bi_z += w * bias_ih[c * GG + HH + i];
            bi_n += w * bias_ih[c * GG + 2 * HH + i];
            bh_r += w * bias_hh[c * GG + i];
            bh_z += w * bias_hh[c * GG + HH + i];
            bh_n += w * bias_hh[c * GG + 2 * HH + i];
            __syncthreads();
        }
    }
    const float rg = 1.f / (1.f + __expf(-(bi_r + g_r + bh_r)));
    const float zg = 1.f / (1.f + __expf(-(bi_z + g_z + bh_z)));
    const float ng = tanhf(bi_n + rg * (g_n + bh_n));
    out[b * HH + i] = (1.f - zg) * ng + zg * h_i;
}

extern "C" void kernel_launch(void* const* d_in, const int* in_sizes, int n_in,
                              void* d_out, int out_size, void* d_ws, size_t ws_size,
                              hipStream_t stream) {
    const float* x       = (const float*)d_in[0];
    const float* h       = (const float*)d_in[1];
    const float* U       = (const float*)d_in[2];
    const float* V       = (const float*)d_in[3];
    const float* bias_ih = (const float*)d_in[4];
    const float* bias_hh = (const float*)d_in[5];
    float* out = (float*)d_out;

    const size_t needed = 256 + (size_t)BB * CC * sizeof(int);
    if (ws_size < needed) {
        gru_cell_naive<<<BB, HH, 0, stream>>>(x, h, U, V, bias_ih, bias_hh, out);
        return;
    }

    int* cnt  = (int*)d_ws;
    int* rows = (int*)((char*)d_ws + 256);

    hipMemsetAsync(cnt, 0, CC * sizeof(int), stream);
    bucket_kernel<<<BB / 256, 256, 0, stream>>>(x, cnt, rows);
    gru_tile_kernel<<<MAXTILES, 256, 0, stream>>>(x, h, U, V, bias_ih, bias_hh,
                                                  cnt, rows, out);
}

// Round 5
// 42.714 us; speedup vs baseline: 2.0597x; 1.0034x over previous
//
#include <hip/hip_runtime.h>
#include <math.h>

#define BB 32768
#define CC 8
#define HH 128
#define RR 16
#define GG (3 * HH)                    // 384
#define TT 16                          // rows per tile
#define MAXTILES ((BB / TT) + CC - 1)  // 2055 upper bound on sum of per-bucket tiles

__device__ __forceinline__ float sigmoidf_fast(float v) {
    return 1.f / (1.f + __expf(-v));
}
__device__ __forceinline__ float tanhf_fast(float v) {
    return 2.f / (1.f + __expf(-2.f * v)) - 1.f;
}

// ---------------- pass 0: zero bucket counters (compute kernel, NOT memset:
// a 32B hipMemsetAsync blit node cost ~41us inside the captured graph) ------
__global__ __launch_bounds__(64) void zero_cnt_kernel(int* __restrict__ cnt) {
    if (threadIdx.x < CC) cnt[threadIdx.x] = 0;
}

// ---------------- pass 1: bucket rows by condition ----------------
__global__ __launch_bounds__(256) void bucket_kernel(
    const float* __restrict__ x, int* __restrict__ cnt, int* __restrict__ rows)
{
    __shared__ int lcnt[CC];
    __shared__ int lbase[CC];
    const int tid = threadIdx.x;
    const int b = blockIdx.x * 256 + tid;

    if (tid < CC) lcnt[tid] = 0;
    __syncthreads();

    const float4 x0 = *(const float4*)(x + b * CC);
    const float4 x1 = *(const float4*)(x + b * CC + 4);
    int c = 0;
    if      (x0.x != 0.f) c = 0;
    else if (x0.y != 0.f) c = 1;
    else if (x0.z != 0.f) c = 2;
    else if (x0.w != 0.f) c = 3;
    else if (x1.x != 0.f) c = 4;
    else if (x1.y != 0.f) c = 5;
    else if (x1.z != 0.f) c = 6;
    else if (x1.w != 0.f) c = 7;

    const int mypos = atomicAdd(&lcnt[c], 1);
    __syncthreads();
    if (tid < CC) lbase[tid] = atomicAdd(&cnt[tid], lcnt[tid]);
    __syncthreads();
    rows[c * BB + lbase[c] + mypos] = b;
}

// ---------------- pass 2: per-condition tiled GRU ----------------
__global__ __launch_bounds__(256, 4) void gru_tile_kernel(
    const float* __restrict__ x, const float* __restrict__ h,
    const float* __restrict__ U, const float* __restrict__ V,
    const float* __restrict__ bih, const float* __restrict__ bhh,
    const int* __restrict__ cnt, const int* __restrict__ rows,
    float* __restrict__ out)
{
    // ---- per-block tile descriptor from cnt[8] (scalar, ~40 ops) ----
    int ncs[CC], tcs[CC];
    #pragma unroll
    for (int q = 0; q < CC; ++q) { ncs[q] = cnt[q]; tcs[q] = (ncs[q] + TT - 1) / TT; }
    const int t = blockIdx.x;
    int c = -1, start = 0, nc = 0, base = 0;
    #pragma unroll
    for (int q = 0; q < CC; ++q) {
        if (c < 0 && t < base + tcs[q]) { c = q; start = (t - base) * TT; nc = ncs[q]; }
        base += tcs[q];
    }
    if (c < 0) return;  // t >= total tiles (<= CC-1 such blocks)

    __shared__ __align__(16) float hs[TT][HH + 4];   // 8.25 KB, stride 132w (16B-mult)
    __shared__ __align__(16) float Vt[RR][HH + 4];   // 8.25 KB
    __shared__ __align__(16) float vhs[TT][20];      // 1.25 KB, stride 80B
    __shared__ int   rloc[TT];
    __shared__ float wloc[TT];

    const int tid = threadIdx.x;

    // stage row indices + weights (threads 0..15)
    if (tid < TT) {
        const int idx = start + tid;
        const int b = (idx < nc) ? rows[c * BB + idx] : -1;
        rloc[tid] = b;
        wloc[tid] = (b >= 0) ? x[b * CC + c] : 0.f;
    }

    // stage Vt (transposed V_c): 2048 floats, 8 per thread
    {
        const float* Vc = V + c * HH * RR;
        #pragma unroll
        for (int k = 0; k < 2; ++k) {
            const int m4 = (tid * 2 + k) * 4;   // element offset in V_c
            const int j  = m4 >> 4;             // /RR
            const int r0 = m4 & 15;
            const float4 v = *(const float4*)(Vc + m4);
            Vt[r0 + 0][j] = v.x; Vt[r0 + 1][j] = v.y;
            Vt[r0 + 2][j] = v.z; Vt[r0 + 3][j] = v.w;
        }
    }

    // stage hs: thread -> (row, seg), 8 floats; re-derive b to avoid a sync
    {
        const int row = tid >> 4, seg = tid & 15;
        const int idx = start + row;
        const int b = (idx < nc) ? rows[c * BB + idx] : -1;
        if (b >= 0) {
            const float4 h0 = *(const float4*)(h + b * HH + seg * 8);
            const float4 h1 = *(const float4*)(h + b * HH + seg * 8 + 4);
            *(float4*)&hs[row][seg * 8]     = h0;
            *(float4*)&hs[row][seg * 8 + 4] = h1;
        } else {
            const float4 z = make_float4(0.f, 0.f, 0.f, 0.f);
            *(float4*)&hs[row][seg * 8]     = z;
            *(float4*)&hs[row][seg * 8 + 4] = z;
        }
    }
    __syncthreads();

    // ---- phase A: vhs[row][r] = w_row * (V_c[:,r] . h_row), 1 dot/thread ----
    {
        const int row = tid >> 4;   // 0..15
        const int r   = tid & 15;
        float s0 = 0.f, s1 = 0.f;
        #pragma unroll
        for (int j4 = 0; j4 < HH / 8; ++j4) {
            const float4 ha = *(const float4*)&hs[row][j4 * 8];
            const float4 va = *(const float4*)&Vt[r][j4 * 8];
            const float4 hb = *(const float4*)&hs[row][j4 * 8 + 4];
            const float4 vb = *(const float4*)&Vt[r][j4 * 8 + 4];
            s0 += ha.x * va.x + ha.y * va.y + ha.z * va.z + ha.w * va.w;
            s1 += hb.x * vb.x + hb.y * vb.y + hb.z * vb.z + hb.w * vb.w;
        }
        vhs[row][r] = (s0 + s1) * wloc[row];
    }
    __syncthreads();

    // ---- phase B: gates; U rows register-resident, reused across 8 rows ----
    const int i    = tid & 127;
    const int half = tid >> 7;
    const float* Up = U + c * GG * RR;

    float ur[RR], uz[RR], un[RR];
    #pragma unroll
    for (int k = 0; k < 4; ++k) {
        const float4 a  = *(const float4*)(Up + i * RR + 4 * k);
        ur[4*k+0] = a.x;  ur[4*k+1] = a.y;  ur[4*k+2] = a.z;  ur[4*k+3] = a.w;
        const float4 bq = *(const float4*)(Up + (HH + i) * RR + 4 * k);
        uz[4*k+0] = bq.x; uz[4*k+1] = bq.y; uz[4*k+2] = bq.z; uz[4*k+3] = bq.w;
        const float4 cq = *(const float4*)(Up + (2 * HH + i) * RR + 4 * k);
        un[4*k+0] = cq.x; un[4*k+1] = cq.y; un[4*k+2] = cq.z; un[4*k+3] = cq.w;
    }
    const float bsr = bih[c * GG + i]          + bhh[c * GG + i];
    const float bsz = bih[c * GG + HH + i]     + bhh[c * GG + HH + i];
    const float bin = bih[c * GG + 2 * HH + i];
    const float bhn = bhh[c * GG + 2 * HH + i];

    #pragma unroll
    for (int m = 0; m < 8; ++m) {
        const int row = half * 8 + m;        // wave-uniform
        const int b = rloc[row];
        if (b < 0) continue;                 // wave-uniform branch
        const float w = wloc[row];

        const float4 v0 = *(const float4*)&vhs[row][0];
        const float4 v1 = *(const float4*)&vhs[row][4];
        const float4 v2 = *(const float4*)&vhs[row][8];
        const float4 v3 = *(const float4*)&vhs[row][12];

        float sra = v0.x*ur[0] + v0.y*ur[1] + v0.z*ur[2] + v0.w*ur[3];
        float srb = v1.x*ur[4] + v1.y*ur[5] + v1.z*ur[6] + v1.w*ur[7];
        sra += v2.x*ur[8]  + v2.y*ur[9]  + v2.z*ur[10] + v2.w*ur[11];
        srb += v3.x*ur[12] + v3.y*ur[13] + v3.z*ur[14] + v3.w*ur[15];
        float sza = v0.x*uz[0] + v0.y*uz[1] + v0.z*uz[2] + v0.w*uz[3];
        float szb = v1.x*uz[4] + v1.y*uz[5] + v1.z*uz[6] + v1.w*uz[7];
        sza += v2.x*uz[8]  + v2.y*uz[9]  + v2.z*uz[10] + v2.w*uz[11];
        szb += v3.x*uz[12] + v3.y*uz[13] + v3.z*uz[14] + v3.w*uz[15];
        float sna = v0.x*un[0] + v0.y*un[1] + v0.z*un[2] + v0.w*un[3];
        float snb = v1.x*un[4] + v1.y*un[5] + v1.z*un[6] + v1.w*un[7];
        sna += v2.x*un[8]  + v2.y*un[9]  + v2.z*un[10] + v2.w*un[11];
        snb += v3.x*un[12] + v3.y*un[13] + v3.z*un[14] + v3.w*un[15];

        const float rg = sigmoidf_fast((sra + srb) + w * bsr);
        const float zg = sigmoidf_fast((sza + szb) + w * bsz);
        const float ng = tanhf_fast(w * bin + rg * ((sna + snb) + w * bhn));
        const float hv = hs[row][i];
        out[b * HH + i] = (1.f - zg) * ng + zg * hv;
    }
}

// ---------------- fallback (round-1 kernel) if ws too small ----------------
__global__ __launch_bounds__(128) void gru_cell_naive(
    const float* __restrict__ x, const float* __restrict__ h,
    const float* __restrict__ U, const float* __restrict__ V,
    const float* __restrict__ bias_ih, const float* __restrict__ bias_hh,
    float* __restrict__ out)
{
    const int b = blockIdx.x;
    const int i = threadIdx.x;
    __shared__ float hsn[HH];
    __shared__ float xsn[CC];
    __shared__ float vhn[RR];
    const float h_i = h[b * HH + i];
    hsn[i] = h_i;
    if (i < CC) xsn[i] = x[b * CC + i];
    __syncthreads();
    float g_r = 0.f, g_z = 0.f, g_n = 0.f;
    float bi_r = 0.f, bi_z = 0.f, bi_n = 0.f;
    float bh_r = 0.f, bh_z = 0.f, bh_n = 0.f;
    for (int c = 0; c < CC; ++c) {
        const float w = xsn[c];
        if (w != 0.f) {
            if (i < RR) {
                const float* Vp = V + c * HH * RR + i;
                float a0 = 0.f;
                for (int j = 0; j < HH; ++j) a0 += Vp[j * RR] * hsn[j];
                vhn[i] = a0;
            }
            __syncthreads();
            const float* Up = U + c * 3 * HH * RR;
            float s_r = 0.f, s_z = 0.f, s_n = 0.f;
            for (int r = 0; r < RR; ++r) s_r += Up[i * RR + r] * vhn[r];
            for (int r = 0; r < RR; ++r) s_z += Up[(HH + i) * RR + r] * vhn[r];
            for (int r = 0; r < RR; ++r) s_n += Up[(2 * HH + i) * RR + r] * vhn[r];
            g_r += w * s_r; g_z += w * s_z; g_n += w * s_n;
            bi_r += w * bias_ih[c * GG + i];
            bi_z += w * bias_ih[c * GG + HH + i];
            bi_n += w * bias_ih[c * GG + 2 * HH + i];
            bh_r += w * bias_hh[c * GG + i];
            bh_z += w * bias_hh[c * GG + HH + i];
            bh_n += w * bias_hh[c * GG + 2 * HH + i];
            __syncthreads();
        }
    }
    const float rg = 1.f / (1.f + __expf(-(bi_r + g_r + bh_r)));
    const float zg = 1.f / (1.f + __expf(-(bi_z + g_z + bh_z)));
    const float ng = tanhf(bi_n + rg * (g_n + bh_n));
    out[b * HH + i] = (1.f - zg) * ng + zg * h_i;
}

extern "C" void kernel_launch(void* const* d_in, const int* in_sizes, int n_in,
                              void* d_out, int out_size, void* d_ws, size_t ws_size,
                              hipStream_t stream) {
    const float* x       = (const float*)d_in[0];
    const float* h       = (const float*)d_in[1];
    const float* U       = (const float*)d_in[2];
    const float* V       = (const float*)d_in[3];
    const float* bias_ih = (const float*)d_in[4];
    const float* bias_hh = (const float*)d_in[5];
    float* out = (float*)d_out;

    const size_t needed = 256 + (size_t)BB * CC * sizeof(int);
    if (ws_size < needed) {
        gru_cell_naive<<<BB, HH, 0, stream>>>(x, h, U, V, bias_ih, bias_hh, out);
        return;
    }

    int* cnt  = (int*)d_ws;
    int* rows = (int*)((char*)d_ws + 256);

    zero_cnt_kernel<<<1, 64, 0, stream>>>(cnt);
    bucket_kernel<<<BB / 256, 256, 0, stream>>>(x, cnt, rows);
    gru_tile_kernel<<<MAXTILES, 256, 0, stream>>>(x, h, U, V, bias_ih, bias_hh,
                                                  cnt, rows, out);
}

// Round 6
// 30.229 us; speedup vs baseline: 2.9104x; 1.4130x over previous
//
#include <hip/hip_runtime.h>
#include <hip/hip_bf16.h>
#include <math.h>

#define BB 32768
#define CC 8
#define HH 128
#define RR 16
#define GG (3 * HH)                    // 384
#define TT 16                          // rows per tile
#define MAXTILES ((BB / TT) + CC - 1)  // 2055

typedef short short8 __attribute__((ext_vector_type(8)));
typedef float f32x4  __attribute__((ext_vector_type(4)));

__device__ __forceinline__ unsigned short f2bf(float f) {
    // fp32 -> bf16 bits, round-to-nearest-even (inputs finite)
    unsigned int u = __float_as_uint(f);
    return (unsigned short)((u + 0x7fffu + ((u >> 16) & 1u)) >> 16);
}
__device__ __forceinline__ float sigmoidf_fast(float v) { return 1.f / (1.f + __expf(-v)); }
__device__ __forceinline__ float tanhf_fast(float v)    { return 2.f / (1.f + __expf(-2.f * v)) - 1.f; }

// ---------------- pass 0: zero bucket counters ----------------
__global__ __launch_bounds__(64) void zero_cnt_kernel(int* __restrict__ cnt) {
    if (threadIdx.x < CC) cnt[threadIdx.x] = 0;
}

// ---------------- pass 1: bucket rows by condition ----------------
__global__ __launch_bounds__(256) void bucket_kernel(
    const float* __restrict__ x, int* __restrict__ cnt, int* __restrict__ rows)
{
    __shared__ int lcnt[CC];
    __shared__ int lbase[CC];
    const int tid = threadIdx.x;
    const int b = blockIdx.x * 256 + tid;

    if (tid < CC) lcnt[tid] = 0;
    __syncthreads();

    const float4 x0 = *(const float4*)(x + b * CC);
    const float4 x1 = *(const float4*)(x + b * CC + 4);
    int c = 0;
    if      (x0.x != 0.f) c = 0;
    else if (x0.y != 0.f) c = 1;
    else if (x0.z != 0.f) c = 2;
    else if (x0.w != 0.f) c = 3;
    else if (x1.x != 0.f) c = 4;
    else if (x1.y != 0.f) c = 5;
    else if (x1.z != 0.f) c = 6;
    else if (x1.w != 0.f) c = 7;

    const int mypos = atomicAdd(&lcnt[c], 1);
    __syncthreads();
    if (tid < CC) lbase[tid] = atomicAdd(&cnt[tid], lcnt[tid]);
    __syncthreads();
    rows[c * BB + lbase[c] + mypos] = b;
}

// ---------------- pass 2: MFMA tile kernel ----------------
// Phase A: vh[16x16] = Hrows[16x128] @ V_c[128x16]   (4x mfma_16x16x32_bf16)
// Phase B: rec[16x384] = vh[16x16(pad32)] @ U_c^T[16x384]  (6 mfma per wave)
__global__ __launch_bounds__(256, 5) void gru_mfma_kernel(
    const float* __restrict__ x, const float* __restrict__ h,
    const float* __restrict__ U, const float* __restrict__ V,
    const float* __restrict__ bih, const float* __restrict__ bhh,
    const int* __restrict__ cnt, const int* __restrict__ rows,
    float* __restrict__ out)
{
    // ---- per-block tile descriptor from cnt[8] ----
    int ncs[CC], tcs[CC];
    #pragma unroll
    for (int q = 0; q < CC; ++q) { ncs[q] = cnt[q]; tcs[q] = (ncs[q] + TT - 1) / TT; }
    const int t = blockIdx.x;
    int c = -1, start = 0, nc = 0, base = 0;
    #pragma unroll
    for (int q = 0; q < CC; ++q) {
        if (c < 0 && t < base + tcs[q]) { c = q; start = (t - base) * TT; nc = ncs[q]; }
        base += tcs[q];
    }
    if (c < 0) return;

    // padded strides: 136 shorts = 272 B (rows land 4 banks apart -> worst 2-way, free)
    __shared__ __align__(16) unsigned short hs_bf[TT][HH + 8];
    __shared__ __align__(16) unsigned short Vt_bf[RR][HH + 8];
    __shared__ __align__(16) unsigned short vhA[4][TT][40];   // per-wave; k<16 data, 16..31 zero
    __shared__ int   rloc[TT];
    __shared__ float wloc[TT];

    const int tid  = threadIdx.x;
    const int lane = tid & 63;
    const int w    = tid >> 6;    // wave id 0..3
    const int r16  = lane & 15;
    const int hi   = lane >> 4;   // 0..3

    // row indices + weights
    if (tid < TT) {
        const int idx = start + tid;
        const int b = (idx < nc) ? rows[c * BB + idx] : -1;
        rloc[tid] = b;
        wloc[tid] = (b >= 0) ? x[b * CC + c] : 0.f;
    }

    // stage h rows as bf16 (one b128 write per thread)
    {
        const int row = tid >> 4, seg = tid & 15;
        const int idx = start + row;
        const int b = (idx < nc) ? rows[c * BB + idx] : -1;
        short8 hv = {0, 0, 0, 0, 0, 0, 0, 0};
        if (b >= 0) {
            const float4 h0 = *(const float4*)(h + b * HH + seg * 8);
            const float4 h1 = *(const float4*)(h + b * HH + seg * 8 + 4);
            hv[0] = (short)f2bf(h0.x); hv[1] = (short)f2bf(h0.y);
            hv[2] = (short)f2bf(h0.z); hv[3] = (short)f2bf(h0.w);
            hv[4] = (short)f2bf(h1.x); hv[5] = (short)f2bf(h1.y);
            hv[6] = (short)f2bf(h1.z); hv[7] = (short)f2bf(h1.w);
        }
        *(short8*)&hs_bf[row][seg * 8] = hv;
    }

    // stage V_c transposed as bf16
    {
        const float* Vc = V + c * HH * RR;
        #pragma unroll
        for (int k = 0; k < 2; ++k) {
            const int m4 = (tid * 2 + k) * 4;  // element offset in V_c ([j][r], r fastest)
            const int j  = m4 >> 4;
            const int r0 = m4 & 15;
            const float4 v = *(const float4*)(Vc + m4);
            Vt_bf[r0 + 0][j] = f2bf(v.x);
            Vt_bf[r0 + 1][j] = f2bf(v.y);
            Vt_bf[r0 + 2][j] = f2bf(v.z);
            Vt_bf[r0 + 3][j] = f2bf(v.w);
        }
    }

    // zero-fill my wave's vhA pad region (k = 16..31)
    if (hi < 2) {
        short8 z = {0, 0, 0, 0, 0, 0, 0, 0};
        *(short8*)&vhA[w][r16][16 + hi * 8] = z;
    }
    __syncthreads();

    // ---- phase A: each wave computes the full 16x16 vh (redundant across waves,
    //      avoids inter-wave sync). A[row=r16][k-block=hi*8], B[col=r16][k-block=hi*8].
    f32x4 acc = {0.f, 0.f, 0.f, 0.f};
    #pragma unroll
    for (int s = 0; s < 4; ++s) {
        const short8 af = *(const short8*)&hs_bf[r16][s * 32 + hi * 8];
        const short8 bf = *(const short8*)&Vt_bf[r16][s * 32 + hi * 8];
        acc = __builtin_amdgcn_mfma_f32_16x16x32_bf16(af, bf, acc, 0, 0, 0);
    }

    // C layout: col = lane&15 (= r), row = 4*hi + q. Fold w, bounce through LDS
    // to transpose into the phase-B A-fragment (same-wave DS ops are in-order).
    int   bq[4];
    float wq[4];
    #pragma unroll
    for (int q = 0; q < 4; ++q) {
        const int rw = 4 * hi + q;
        bq[q] = rloc[rw];
        wq[q] = wloc[rw];
        vhA[w][rw][r16] = f2bf(acc[q] * wq[q]);
    }
    const short8 a2 = *(const short8*)&vhA[w][r16][hi * 8];  // A[row=r16][k=8*hi+j]

    // ---- phase B: wave w handles i-blocks {2w, 2w+1}; gates r/z/n are col-tiles
    //      t, 8+t, 16+t which share intra-tile position -> aligned accumulators.
    const float* Uc = U + c * GG * RR;
    #pragma unroll
    for (int d = 0; d < 2; ++d) {
        const int icol = 16 * (2 * w + d) + r16;

        short8 bR = {0,0,0,0,0,0,0,0}, bZ = {0,0,0,0,0,0,0,0}, bN = {0,0,0,0,0,0,0,0};
        if (hi < 2) {  // k = 8*hi + j < 16 real, rest zero-padded
            const float* ur = Uc + (0 * HH + icol) * RR + 8 * hi;
            const float* uz = Uc + (1 * HH + icol) * RR + 8 * hi;
            const float* un = Uc + (2 * HH + icol) * RR + 8 * hi;
            const float4 r0 = *(const float4*)ur, r1 = *(const float4*)(ur + 4);
            const float4 z0 = *(const float4*)uz, z1 = *(const float4*)(uz + 4);
            const float4 n0 = *(const float4*)un, n1 = *(const float4*)(un + 4);
            bR[0]=(short)f2bf(r0.x); bR[1]=(short)f2bf(r0.y); bR[2]=(short)f2bf(r0.z); bR[3]=(short)f2bf(r0.w);
            bR[4]=(short)f2bf(r1.x); bR[5]=(short)f2bf(r1.y); bR[6]=(short)f2bf(r1.z); bR[7]=(short)f2bf(r1.w);
            bZ[0]=(short)f2bf(z0.x); bZ[1]=(short)f2bf(z0.y); bZ[2]=(short)f2bf(z0.z); bZ[3]=(short)f2bf(z0.w);
            bZ[4]=(short)f2bf(z1.x); bZ[5]=(short)f2bf(z1.y); bZ[6]=(short)f2bf(z1.z); bZ[7]=(short)f2bf(z1.w);
            bN[0]=(short)f2bf(n0.x); bN[1]=(short)f2bf(n0.y); bN[2]=(short)f2bf(n0.z); bN[3]=(short)f2bf(n0.w);
            bN[4]=(short)f2bf(n1.x); bN[5]=(short)f2bf(n1.y); bN[6]=(short)f2bf(n1.z); bN[7]=(short)f2bf(n1.w);
        }
        const f32x4 zi = {0.f, 0.f, 0.f, 0.f};
        const f32x4 aR = __builtin_amdgcn_mfma_f32_16x16x32_bf16(a2, bR, zi, 0, 0, 0);
        const f32x4 aZ = __builtin_amdgcn_mfma_f32_16x16x32_bf16(a2, bZ, zi, 0, 0, 0);
        const f32x4 aN = __builtin_amdgcn_mfma_f32_16x16x32_bf16(a2, bN, zi, 0, 0, 0);

        const float bihr = bih[c * GG + icol];
        const float bihz = bih[c * GG + HH + icol];
        const float bihn = bih[c * GG + 2 * HH + icol];
        const float bhhr = bhh[c * GG + icol];
        const float bhhz = bhh[c * GG + HH + icol];
        const float bhhn = bhh[c * GG + 2 * HH + icol];

        #pragma unroll
        for (int q = 0; q < 4; ++q) {
            const int b = bq[q];
            if (b >= 0) {
                const float w_ = wq[q];
                const float rg = sigmoidf_fast(aR[q] + w_ * (bihr + bhhr));
                const float zg = sigmoidf_fast(aZ[q] + w_ * (bihz + bhhz));
                const float ng = tanhf_fast(w_ * bihn + rg * (aN[q] + w_ * bhhn));
                const float hv = h[b * HH + icol];
                out[b * HH + icol] = (1.f - zg) * ng + zg * hv;
            }
        }
    }
}

// ---------------- fallback if ws too small ----------------
__global__ __launch_bounds__(128) void gru_cell_naive(
    const float* __restrict__ x, const float* __restrict__ h,
    const float* __restrict__ U, const float* __restrict__ V,
    const float* __restrict__ bias_ih, const float* __restrict__ bias_hh,
    float* __restrict__ out)
{
    const int b = blockIdx.x;
    const int i = threadIdx.x;
    __shared__ float hsn[HH];
    __shared__ float xsn[CC];
    __shared__ float vhn[RR];
    const float h_i = h[b * HH + i];
    hsn[i] = h_i;
    if (i < CC) xsn[i] = x[b * CC + i];
    __syncthreads();
    float g_r = 0.f, g_z = 0.f, g_n = 0.f;
    float bi_r = 0.f, bi_z = 0.f, bi_n = 0.f;
    float bh_r = 0.f, bh_z = 0.f, bh_n = 0.f;
    for (int c = 0; c < CC; ++c) {
        const float w = xsn[c];
        if (w != 0.f) {
            if (i < RR) {
                const float* Vp = V + c * HH * RR + i;
                float a0 = 0.f;
                for (int j = 0; j < HH; ++j) a0 += Vp[j * RR] * hsn[j];
                vhn[i] = a0;
            }
            __syncthreads();
            const float* Up = U + c * 3 * HH * RR;
            float s_r = 0.f, s_z = 0.f, s_n = 0.f;
            for (int r = 0; r < RR; ++r) s_r += Up[i * RR + r] * vhn[r];
            for (int r = 0; r < RR; ++r) s_z += Up[(HH + i) * RR + r] * vhn[r];
            for (int r = 0; r < RR; ++r) s_n += Up[(2 * HH + i) * RR + r] * vhn[r];
            g_r += w * s_r; g_z += w * s_z; g_n += w * s_n;
            bi_r += w * bias_ih[c * GG + i];
            bi_z += w * bias_ih[c * GG + HH + i];
            bi_n += w * bias_ih[c * GG + 2 * HH + i];
            bh_r += w * bias_hh[c * GG + i];
            bh_z += w * bias_hh[c * GG + HH + i];
            bh_n += w * bias_hh[c * GG + 2 * HH + i];
            __syncthreads();
        }
    }
    const float rg = 1.f / (1.f + __expf(-(bi_r + g_r + bh_r)));
    const float zg = 1.f / (1.f + __expf(-(bi_z + g_z + bh_z)));
    const float ng = tanhf(bi_n + rg * (g_n + bh_n));
    out[b * HH + i] = (1.f - zg) * ng + zg * h_i;
}

extern "C" void kernel_launch(void* const* d_in, const int* in_sizes, int n_in,
                              void* d_out, int out_size, void* d_ws, size_t ws_size,
                              hipStream_t stream) {
    const float* x       = (const float*)d_in[0];
    const float* h       = (const float*)d_in[1];
    const float* U       = (const float*)d_in[2];
    const float* V       = (const float*)d_in[3];
    const float* bias_ih = (const float*)d_in[4];
    const float* bias_hh = (const float*)d_in[5];
    float* out = (float*)d_out;

    const size_t needed = 256 + (size_t)BB * CC * sizeof(int);
    if (ws_size < needed) {
        gru_cell_naive<<<BB, HH, 0, stream>>>(x, h, U, V, bias_ih, bias_hh, out);
        return;
    }

    int* cnt  = (int*)d_ws;
    int* rows = (int*)((char*)d_ws + 256);

    zero_cnt_kernel<<<1, 64, 0, stream>>>(cnt);
    bucket_kernel<<<BB / 256, 256, 0, stream>>>(x, cnt, rows);
    gru_mfma_kernel<<<MAXTILES, 256, 0, stream>>>(x, h, U, V, bias_ih, bias_hh,
                                                  cnt, rows, out);
}

// Round 10
// 28.836 us; speedup vs baseline: 3.0510x; 1.0483x over previous
//
#include <hip/hip_runtime.h>
#include <math.h>

#define BB 32768
#define CC 8
#define HH 128
#define RR 16
#define GG (3 * HH)                    // 384
#define TT 16                          // rows per tile
#define MAXTILES ((BB / TT) + CC - 1)  // 2055

// ---- workspace layout ----
#define ROWS_OFF 256
#define UBF_OFF  (ROWS_OFF + BB * CC * 4)        // 1,048,832 (16B aligned)
#define VBF_OFF  (UBF_OFF + CC * GG * RR * 2)    // + 98,304
#define WS_NEEDED (VBF_OFF + CC * RR * HH * 2)   // + 32,768

typedef short short8 __attribute__((ext_vector_type(8)));
typedef float f32x4  __attribute__((ext_vector_type(4)));

__device__ __forceinline__ unsigned short f2bf(float f) {
    unsigned int u = __float_as_uint(f);
    return (unsigned short)((u + 0x7fffu + ((u >> 16) & 1u)) >> 16);
}
__device__ __forceinline__ float sigmoidf_fast(float v) { return 1.f / (1.f + __expf(-v)); }
__device__ __forceinline__ float tanhf_fast(float v)    { return 2.f / (1.f + __expf(-2.f * v)) - 1.f; }

// ---------------- pass 0: convert U/V to bf16 once + zero counters ----------------
// Ubf: natural layout [c][col(384)][k(16)].  Vtbf: transposed [c][r(16)][j(128)].
__global__ __launch_bounds__(256) void prep_kernel(
    const float* __restrict__ U, const float* __restrict__ V,
    unsigned short* __restrict__ Ubf, unsigned short* __restrict__ Vtbf,
    int* __restrict__ cnt)
{
    const int id = blockIdx.x * 256 + threadIdx.x;
    if (blockIdx.x == 0 && threadIdx.x < CC) cnt[threadIdx.x] = 0;
    if (id < CC * GG * RR) {
        Ubf[id] = f2bf(U[id]);                       // coalesced in/out
    } else {
        const int e = id - CC * GG * RR;             // < CC*RR*HH = 16384
        const int c = e >> 11, rem = e & 2047;
        const int r = rem >> 7, j = rem & 127;
        Vtbf[e] = f2bf(V[c * (HH * RR) + j * RR + r]);
    }
}

// ---------------- pass 1: bucket rows by condition ----------------
__global__ __launch_bounds__(256) void bucket_kernel(
    const float* __restrict__ x, int* __restrict__ cnt, int* __restrict__ rows)
{
    __shared__ int lcnt[CC];
    __shared__ int lbase[CC];
    const int tid = threadIdx.x;
    const int b = blockIdx.x * 256 + tid;

    if (tid < CC) lcnt[tid] = 0;
    __syncthreads();

    const float4 x0 = *(const float4*)(x + b * CC);
    const float4 x1 = *(const float4*)(x + b * CC + 4);
    int c = 0;
    if      (x0.x != 0.f) c = 0;
    else if (x0.y != 0.f) c = 1;
    else if (x0.z != 0.f) c = 2;
    else if (x0.w != 0.f) c = 3;
    else if (x1.x != 0.f) c = 4;
    else if (x1.y != 0.f) c = 5;
    else if (x1.z != 0.f) c = 6;
    else if (x1.w != 0.f) c = 7;

    const int mypos = atomicAdd(&lcnt[c], 1);
    __syncthreads();
    if (tid < CC) lbase[tid] = atomicAdd(&cnt[tid], lcnt[tid]);
    __syncthreads();
    rows[c * BB + lbase[c] + mypos] = b;
}

// ---------------- pass 2: MFMA tile kernel ----------------
// Phase A: vh[16x16] = Hrows[16x128] @ V_c[128x16]   (4x mfma_16x16x32_bf16)
// Phase B: rec[16x384] = vh[16x16(pad32)] @ U_c^T    (6 mfma per wave)
__global__ __launch_bounds__(256) void gru_mfma_kernel(
    const float* __restrict__ x, const float* __restrict__ h,
    const unsigned short* __restrict__ Ubf, const unsigned short* __restrict__ Vtbf,
    const float* __restrict__ bih, const float* __restrict__ bhh,
    const int* __restrict__ cnt, const int* __restrict__ rows,
    float* __restrict__ out)
{
    // ---- per-block tile descriptor from cnt[8] ----
    int ncs[CC], tcs[CC];
    #pragma unroll
    for (int q = 0; q < CC; ++q) { ncs[q] = cnt[q]; tcs[q] = (ncs[q] + TT - 1) / TT; }
    const int t = blockIdx.x;
    int c = -1, start = 0, nc = 0, base = 0;
    #pragma unroll
    for (int q = 0; q < CC; ++q) {
        if (c < 0 && t < base + tcs[q]) { c = q; start = (t - base) * TT; nc = ncs[q]; }
        base += tcs[q];
    }
    if (c < 0) return;

    __shared__ __align__(16) unsigned short hs_bf[TT][HH + 8];   // 272B stride
    __shared__ __align__(16) unsigned short Vt_bf[RR][HH + 8];
    __shared__ __align__(16) unsigned short vhA[4][TT][40];      // per-wave bounce
    __shared__ int   rloc[TT];
    __shared__ float wloc[TT];

    const int tid  = threadIdx.x;
    const int lane = tid & 63;
    const int w    = tid >> 6;    // wave id 0..3
    const int r16  = lane & 15;
    const int hi   = lane >> 4;   // 0..3

    // row indices + weights
    if (tid < TT) {
        const int idx = start + tid;
        const int b = (idx < nc) ? rows[c * BB + idx] : -1;
        rloc[tid] = b;
        wloc[tid] = (b >= 0) ? x[b * CC + c] : 0.f;
    }

    // stage h rows as bf16 (one b128 write per thread)
    {
        const int row = tid >> 4, seg = tid & 15;
        const int idx = start + row;
        const int b = (idx < nc) ? rows[c * BB + idx] : -1;
        short8 hv = {0, 0, 0, 0, 0, 0, 0, 0};
        if (b >= 0) {
            const float4 h0 = *(const float4*)(h + b * HH + seg * 8);
            const float4 h1 = *(const float4*)(h + b * HH + seg * 8 + 4);
            hv[0] = (short)f2bf(h0.x); hv[1] = (short)f2bf(h0.y);
            hv[2] = (short)f2bf(h0.z); hv[3] = (short)f2bf(h0.w);
            hv[4] = (short)f2bf(h1.x); hv[5] = (short)f2bf(h1.y);
            hv[6] = (short)f2bf(h1.z); hv[7] = (short)f2bf(h1.w);
        }
        *(short8*)&hs_bf[row][seg * 8] = hv;
    }

    // stage Vt from precomputed bf16 (one b128 load+store per thread)
    {
        const unsigned short* Vc = Vtbf + c * (RR * HH);
        const int r = tid >> 4, j0 = (tid & 15) * 8;
        *(short8*)&Vt_bf[r][j0] = *(const short8*)(Vc + r * HH + j0);
    }

    // zero-fill my wave's vhA pad region (k = 16..31)
    if (hi < 2) {
        short8 z = {0, 0, 0, 0, 0, 0, 0, 0};
        *(short8*)&vhA[w][r16][16 + hi * 8] = z;
    }
    __syncthreads();

    // ---- phase A (redundant per wave; avoids inter-wave sync) ----
    f32x4 acc = {0.f, 0.f, 0.f, 0.f};
    #pragma unroll
    for (int s = 0; s < 4; ++s) {
        const short8 af = *(const short8*)&hs_bf[r16][s * 32 + hi * 8];
        const short8 bf = *(const short8*)&Vt_bf[r16][s * 32 + hi * 8];
        acc = __builtin_amdgcn_mfma_f32_16x16x32_bf16(af, bf, acc, 0, 0, 0);
    }

    // C layout: col = r16, row = 4*hi + q. Fold w; bounce via LDS to transpose
    // into phase-B A-fragment (same-wave DS ops, lgkm-ordered).
    int   bq[4];
    float wq[4];
    #pragma unroll
    for (int q = 0; q < 4; ++q) {
        const int rw = 4 * hi + q;
        bq[q] = rloc[rw];
        wq[q] = wloc[rw];
        vhA[w][rw][r16] = f2bf(acc[q] * wq[q]);
    }
    const short8 a2 = *(const short8*)&vhA[w][r16][hi * 8];

    // ---- phase B: wave w -> i-blocks {2w, 2w+1}; B-frags straight from Ubf ----
    const unsigned short* Uc = Ubf + (size_t)c * GG * RR;
    #pragma unroll
    for (int d = 0; d < 2; ++d) {
        const int icol = 16 * (2 * w + d) + r16;

        short8 bR = {0,0,0,0,0,0,0,0}, bZ = {0,0,0,0,0,0,0,0}, bN = {0,0,0,0,0,0,0,0};
        if (hi < 2) {   // k = 8*hi + j < 16 real, k>=16 zero (A pad is zero too)
            bR = *(const short8*)(Uc + (0 * HH + icol) * RR + 8 * hi);
            bZ = *(const short8*)(Uc + (1 * HH + icol) * RR + 8 * hi);
            bN = *(const short8*)(Uc + (2 * HH + icol) * RR + 8 * hi);
        }
        const f32x4 zi = {0.f, 0.f, 0.f, 0.f};
        const f32x4 aR = __builtin_amdgcn_mfma_f32_16x16x32_bf16(a2, bR, zi, 0, 0, 0);
        const f32x4 aZ = __builtin_amdgcn_mfma_f32_16x16x32_bf16(a2, bZ, zi, 0, 0, 0);
        const f32x4 aN = __builtin_amdgcn_mfma_f32_16x16x32_bf16(a2, bN, zi, 0, 0, 0);

        const float bihr = bih[c * GG + icol];
        const float bihz = bih[c * GG + HH + icol];
        const float bihn = bih[c * GG + 2 * HH + icol];
        const float bhhr = bhh[c * GG + icol];
        const float bhhz = bhh[c * GG + HH + icol];
        const float bhhn = bhh[c * GG + 2 * HH + icol];

        #pragma unroll
        for (int q = 0; q < 4; ++q) {
            const int b = bq[q];
            if (b >= 0) {
                const float w_ = wq[q];
                const float rg = sigmoidf_fast(aR[q] + w_ * (bihr + bhhr));
                const float zg = sigmoidf_fast(aZ[q] + w_ * (bihz + bhhz));
                const float ng = tanhf_fast(w_ * bihn + rg * (aN[q] + w_ * bhhn));
                const float hv = h[b * HH + icol];
                out[b * HH + icol] = (1.f - zg) * ng + zg * hv;
            }
        }
    }
}

// ---------------- fallback if ws too small ----------------
__global__ __launch_bounds__(128) void gru_cell_naive(
    const float* __restrict__ x, const float* __restrict__ h,
    const float* __restrict__ U, const float* __restrict__ V,
    const float* __restrict__ bias_ih, const float* __restrict__ bias_hh,
    float* __restrict__ out)
{
    const int b = blockIdx.x;
    const int i = threadIdx.x;
    __shared__ float hsn[HH];
    __shared__ float xsn[CC];
    __shared__ float vhn[RR];
    const float h_i = h[b * HH + i];
    hsn[i] = h_i;
    if (i < CC) xsn[i] = x[b * CC + i];
    __syncthreads();
    float g_r = 0.f, g_z = 0.f, g_n = 0.f;
    float bi_r = 0.f, bi_z = 0.f, bi_n = 0.f;
    float bh_r = 0.f, bh_z = 0.f, bh_n = 0.f;
    for (int c = 0; c < CC; ++c) {
        const float w = xsn[c];
        if (w != 0.f) {
            if (i < RR) {
                const float* Vp = V + c * HH * RR + i;
                float a0 = 0.f;
                for (int j = 0; j < HH; ++j) a0 += Vp[j * RR] * hsn[j];
                vhn[i] = a0;
            }
            __syncthreads();
            const float* Up = U + c * 3 * HH * RR;
            float s_r = 0.f, s_z = 0.f, s_n = 0.f;
            for (int r = 0; r < RR; ++r) s_r += Up[i * RR + r] * vhn[r];
            for (int r = 0; r < RR; ++r) s_z += Up[(HH + i) * RR + r] * vhn[r];
            for (int r = 0; r < RR; ++r) s_n += Up[(2 * HH + i) * RR + r] * vhn[r];
            g_r += w * s_r; g_z += w * s_z; g_n += w * s_n;
            bi_r += w * bias_ih[c * GG + i];
            bi_z += w * bias_ih[c * GG + HH + i];
            bi_n += w * bias_ih[c * GG + 2 * HH + i];
            bh_r += w * bias_hh[c * GG + i];
            bh_z += w * bias_hh[c * GG + HH + i];
            bh_n += w * bias_hh[c * GG + 2 * HH + i];
            __syncthreads();
        }
    }
    const float rg = 1.f / (1.f + __expf(-(bi_r + g_r + bh_r)));
    const float zg = 1.f / (1.f + __expf(-(bi_z + g_z + bh_z)));
    const float ng = tanhf(bi_n + rg * (g_n + bh_n));
    out[b * HH + i] = (1.f - zg) * ng + zg * h_i;
}

extern "C" void kernel_launch(void* const* d_in, const int* in_sizes, int n_in,
                              void* d_out, int out_size, void* d_ws, size_t ws_size,
                              hipStream_t stream) {
    const float* x       = (const float*)d_in[0];
    const float* h       = (const float*)d_in[1];
    const float* U       = (const float*)d_in[2];
    const float* V       = (const float*)d_in[3];
    const float* bias_ih = (const float*)d_in[4];
    const float* bias_hh = (const float*)d_in[5];
    float* out = (float*)d_out;

    if (ws_size < (size_t)WS_NEEDED) {
        gru_cell_naive<<<BB, HH, 0, stream>>>(x, h, U, V, bias_ih, bias_hh, out);
        return;
    }

    int*            cnt  = (int*)d_ws;
    int*            rows = (int*)((char*)d_ws + ROWS_OFF);
    unsigned short* Ubf  = (unsigned short*)((char*)d_ws + UBF_OFF);
    unsigned short* Vtbf = (unsigned short*)((char*)d_ws + VBF_OFF);

    prep_kernel<<<(CC * GG * RR + CC * RR * HH) / 256, 256, 0, stream>>>(U, V, Ubf, Vtbf, cnt);
    bucket_kernel<<<BB / 256, 256, 0, stream>>>(x, cnt, rows);
    gru_mfma_kernel<<<MAXTILES, 256, 0, stream>>>(x, h, Ubf, Vtbf, bias_ih, bias_hh,
                                                  cnt, rows, out);
}